// Round 15
// baseline (324.865 us; speedup 1.0000x reference)
//
#include <hip/hip_runtime.h>
#include <math.h>

#define NUM_NODES 94
#define SEQ_LEN 784
#define OUT_CLASSES 10

#define TWO_GAMMA 0.2f
#define OM2 0.0503551324598949f            // (2*pi/28)^2
#define INV_SQRT_N 0.103142124625879       // 1/sqrt(94)
#define LOG2E 1.4426950408889634
// exp2 arg = 2A*log2e -> fold 2*INV_SQRT_N*LOG2E into all I-path weights
#define WSCALE ((float)(2.0 * INV_SQRT_N * LOG2E))

typedef _Float16 h2 __attribute__((ext_vector_type(2)));
typedef _Float16 h4 __attribute__((ext_vector_type(4)));
typedef float f4 __attribute__((ext_vector_type(4)));

__device__ __forceinline__ float dpp_xor1(float x) {   // quad_perm(1,0,3,2)
    return __int_as_float(__builtin_amdgcn_mov_dpp(__float_as_int(x), 0xB1, 0xF, 0xF, true));
}
__device__ __forceinline__ float dpp_xor2(float x) {   // quad_perm(2,3,0,1)
    return __int_as_float(__builtin_amdgcn_mov_dpp(__float_as_int(x), 0x4E, 0xF, 0xF, true));
}
__device__ __forceinline__ float dpp_mir8(float x) {   // ROW_HALF_MIRROR: i<->i^7
    return __int_as_float(__builtin_amdgcn_mov_dpp(__float_as_int(x), 0x141, 0xF, 0xF, true));
}

__device__ __forceinline__ float dot2(h2 a, h2 b, float c) {
#if __has_builtin(__builtin_amdgcn_fdot2)
    return __builtin_amdgcn_fdot2(a, b, c, false);   // v_dot2_f32_f16
#else
    return c + (float)a[0] * (float)b[0] + (float)a[1] * (float)b[1];
#endif
}

// R13/R14 skeleton (best=272us, absmax 1.95e-3). R15: the 508 busy cyc/step
// audit pins v_dot2_f32_f16 as half-rate (72 dots = 288 cyc, the largest
// line item). Swap the dot engine: accumulate per-row products in an h2
// accumulator via v_pk_fma_f16 (FULL rate, 2 MACs/2cyc; each f16 half sums
// only 6 products), then combine halves in f32 with ONE dot2(P2,{1,1},0)
// (exact f32 cvt+add). Dots: 288 -> ~192 cyc. Everything else unchanged.
__global__
__attribute__((amdgpu_flat_work_group_size(64, 64), amdgpu_waves_per_eu(1, 4)))
void horn_kernel(
    const float* __restrict__ input,   // (1024, 784)
    const float* __restrict__ w_ih,    // (94, 1)
    const float* __restrict__ b_ih,    // (94)
    const float* __restrict__ w_hh,    // (94, 94)
    const float* __restrict__ b_hh,    // (94)
    const float* __restrict__ w_ro,    // (10, 94)
    const float* __restrict__ b_ro,    // (10)
    float* __restrict__ out)           // (1024, 10)
{
    __shared__ __align__(16) _Float16 ysh[96];        // y exchange (f16)
    __shared__ __align__(16) float    sin_l[SEQ_LEN]; // input row (f32)
    __shared__ __align__(16) float    xsh[96];        // epilogue x gather

    const int lane = threadIdx.x;      // 0..63
    const int g    = lane >> 3;        // row-group: rows 12g..12g+11
    const int lw   = lane & 7;         // col-chunk: cols 12lw..12lw+11
    const int bb   = blockIdx.x;       // batch element

    const int b0  = lane & 1, b1 = (lane >> 1) & 1, b2v = (lane >> 2) & 1;
    const int c0i = b0 ^ b2v;
    const int c1i = b1 ^ b2v;
    const int c2i = b2v;

    const int row0 = 12 * g, col0 = 12 * lw;

    // ---- preload input row to LDS (784 floats, float4-coalesced) ----
    {
        const f4* in4 = (const f4*)(input + (size_t)bb * SEQ_LEN);
        f4* s4 = (f4*)sin_l;
        #pragma unroll 1
        for (int i = lane; i < SEQ_LEN / 4; i += 64) s4[i] = in4[i];
    }

    // ---- W block with folded row permutation (select-free butterfly),
    //      f16-packed, pre-scaled ----
    h2 w2[12][6];
    #pragma unroll
    for (int j = 0; j < 12; j++) {
        int rr;
        if (j < 8) {
            rr = row0 + 4 * (((j >> 2) & 1) ^ c2i)
                      + 2 * (((j >> 1) & 1) ^ c1i)
                      +     ((j & 1) ^ c0i);
        } else {
            const int jj = j - 8;
            rr = row0 + 8 + 2 * (((jj >> 1) & 1) ^ c1i)
                          +     ((jj & 1) ^ c0i);
        }
        #pragma unroll
        for (int c = 0; c < 12; c++) {
            const int cc = col0 + c;
            float v = (rr < NUM_NODES && cc < NUM_NODES)
                        ? w_hh[rr * NUM_NODES + cc] * WSCALE : 0.0f;
            w2[j][c >> 1][c & 1] = (_Float16)v;
        }
    }

    // Owned rows (verified machinery R6-R14):
    const int nA = row0 + 4 * c2i + 2 * c1i + c0i;
    const int nB = row0 + 8 + 2 * c1i + c0i;
    const float wihA  = (nA < NUM_NODES) ? w_ih[nA] * WSCALE : 0.0f;
    const float biasA = (nA < NUM_NODES) ? (b_ih[nA] + b_hh[nA]) * WSCALE : 0.0f;
    const float wihB  = (nB < NUM_NODES) ? w_ih[nB] * WSCALE : 0.0f;
    const float biasB = (nB < NUM_NODES) ? (b_ih[nB] + b_hh[nB]) * WSCALE : 0.0f;

    float xA = 0.0f, yA = 0.0f, xB = 0.0f, yB = 0.0f;

    // Init published y (nA unique over 64 lanes, nB pair-duplicated).
    ysh[nA] = (_Float16)0.0f;
    ysh[nB] = (_Float16)0.0f;
    // One-time ordering point: init writes + input preload before the loop.
    asm volatile("s_waitcnt lgkmcnt(0) vmcnt(0)" ::: "memory");

    const h4* yv4 = (const h4*)&ysh[col0];     // byte 24*lw: 8B-aligned

    const h2 hones = {(_Float16)1.0f, (_Float16)1.0f};

    float st = sin_l[0];                       // step-0 input (prefetched)

    #pragma unroll 2
    for (int t = 0; t < SEQ_LEN; t++) {
        // ---- read own 12-col y chunk; prefetch NEXT step's input scalar ----
        h4 Y0 = yv4[0], Y1 = yv4[1], Y2 = yv4[2];
        const int tn = (t + 1 < SEQ_LEN) ? t + 1 : (SEQ_LEN - 1);
        float stn = sin_l[tn];
        h2 yy0 = __builtin_shufflevector(Y0, Y0, 0, 1);
        h2 yy1 = __builtin_shufflevector(Y0, Y0, 2, 3);
        h2 yy2 = __builtin_shufflevector(Y1, Y1, 0, 1);
        h2 yy3 = __builtin_shufflevector(Y1, Y1, 2, 3);
        h2 yy4 = __builtin_shufflevector(Y2, Y2, 0, 1);
        h2 yy5 = __builtin_shufflevector(Y2, Y2, 2, 3);

        // ---- 12 rows x 12 cols: 72 v_pk_fma_f16 (full rate), then one
        //      dot2 per row to combine the two f16 halves exactly in f32 ----
        float P[12];
        #pragma unroll
        for (int i = 0; i < 12; i++) {
            h2 p2 = w2[i][0] * yy0;            // each half sums 6 products
            p2 = w2[i][1] * yy1 + p2;
            p2 = w2[i][2] * yy2 + p2;
            p2 = w2[i][3] * yy3 + p2;
            p2 = w2[i][4] * yy4 + p2;
            p2 = w2[i][5] * yy5 + p2;
            P[i] = dot2(p2, hones, 0.0f);      // f32: p2.lo + p2.hi
        }

        // ---- select-free butterfly (row permutation folded at load) ----
        float Q0 = P[0]  + dpp_xor1(P[1]);
        float Q1 = P[2]  + dpp_xor1(P[3]);
        float Q2 = P[4]  + dpp_xor1(P[5]);
        float Q3 = P[6]  + dpp_xor1(P[7]);
        float Q4 = P[8]  + dpp_xor1(P[9]);
        float Q5 = P[10] + dpp_xor1(P[11]);
        float R0 = Q0 + dpp_xor2(Q1);
        float R1 = Q2 + dpp_xor2(Q3);
        float R2 = Q4 + dpp_xor2(Q5);
        float SA = R0 + dpp_mir8(R1);          // full dot, row nA
        float SB = R2 + dpp_mir8(R2);          // full dot, row nB

        // ---- dynamics (f32 state; st already in a register) ----
        float eA = __builtin_amdgcn_exp2f(fmaf(st, wihA, biasA) + SA);
        float aA = 0.5f - __builtin_amdgcn_rcpf(eA + 1.0f);  // 0.5*tanh(A)
        aA = fmaf(-TWO_GAMMA, yA, aA);
        aA = fmaf(-OM2, xA, aA);
        xA += yA;  yA += aA;
        ysh[nA] = (_Float16)yA;                // publish ASAP

        float eB = __builtin_amdgcn_exp2f(fmaf(st, wihB, biasB) + SB);
        float aB = 0.5f - __builtin_amdgcn_rcpf(eB + 1.0f);
        aB = fmaf(-TWO_GAMMA, yB, aB);
        aB = fmaf(-OM2, xB, aB);
        xB += yB;  yB += aB;
        ysh[nB] = (_Float16)yB;                // pair-duplicate: benign
        // NO fence: DS pipe is in-order per wave; the next iteration's
        // ds_read is ordered after these writes (data-wait compiler-emitted).

        st = stn;
    }

    // ---- epilogue: gather x (f32), project to classes ----
    xsh[nA] = xA;
    xsh[nB] = xB;
    asm volatile("s_waitcnt lgkmcnt(0)" ::: "memory");

    if (lane < OUT_CLASSES) {
        float acc = b_ro[lane];
        #pragma unroll 2
        for (int j = 0; j < NUM_NODES; j++) {
            acc += xsh[j] * w_ro[lane * NUM_NODES + j];
        }
        out[(size_t)bb * OUT_CLASSES + lane] = acc;
    }
}

extern "C" void kernel_launch(void* const* d_in, const int* in_sizes, int n_in,
                              void* d_out, int out_size, void* d_ws, size_t ws_size,
                              hipStream_t stream) {
    const float* input = (const float*)d_in[0];
    const float* w_ih  = (const float*)d_in[1];
    const float* b_ih  = (const float*)d_in[2];
    const float* w_hh  = (const float*)d_in[3];
    const float* b_hh  = (const float*)d_in[4];
    const float* w_ro  = (const float*)d_in[5];
    const float* b_ro  = (const float*)d_in[6];
    float* out = (float*)d_out;

    const int batch = in_sizes[0] / SEQ_LEN;   // 1024
    dim3 grid(batch);                          // 1 element per 1-wave block
    dim3 block(64);

    hipLaunchKernelGGL(horn_kernel, grid, block, 0, stream,
                       input, w_ih, b_ih, w_hh, b_hh, w_ro, b_ro, out);
}

// Round 16
// 308.188 us; speedup vs baseline: 1.0541x; 1.0541x over previous
//
#include <hip/hip_runtime.h>
#include <math.h>

#define NUM_NODES 94
#define SEQ_LEN 784
#define OUT_CLASSES 10

#define TWO_GAMMA 0.2f
#define OM2 0.0503551324598949f            // (2*pi/28)^2
#define INV_SQRT_N 0.103142124625879       // 1/sqrt(94)
#define LOG2E 1.4426950408889634
// exp2 arg = 2A*log2e -> fold 2*INV_SQRT_N*LOG2E into all I-path weights
#define WSCALE ((float)(2.0 * INV_SQRT_N * LOG2E))

typedef _Float16 h2 __attribute__((ext_vector_type(2)));
typedef _Float16 h4 __attribute__((ext_vector_type(4)));
typedef float f2 __attribute__((ext_vector_type(2)));
typedef float f4 __attribute__((ext_vector_type(4)));

__device__ __forceinline__ float dpp_xor1(float x) {   // quad_perm(1,0,3,2)
    return __int_as_float(__builtin_amdgcn_mov_dpp(__float_as_int(x), 0xB1, 0xF, 0xF, true));
}
__device__ __forceinline__ float dpp_xor2(float x) {   // quad_perm(2,3,0,1)
    return __int_as_float(__builtin_amdgcn_mov_dpp(__float_as_int(x), 0x4E, 0xF, 0xF, true));
}
__device__ __forceinline__ float dpp_mir8(float x) {   // ROW_HALF_MIRROR: i<->i^7
    return __int_as_float(__builtin_amdgcn_mov_dpp(__float_as_int(x), 0x141, 0xF, 0xF, true));
}

__device__ __forceinline__ float dot2(h2 a, h2 b, float c) {
#if __has_builtin(__builtin_amdgcn_fdot2)
    return __builtin_amdgcn_fdot2(a, b, c, false);   // v_dot2_f32_f16
#else
    return c + (float)a[0] * (float)b[0] + (float)a[1] * (float)b[1];
#endif
}

// R14 revert (R15's pk_fma_f16 dot engine regressed: dot2 and pk_fma_f16 are
// the same rate, the 12 combine insts were pure overhead). One micro-op on
// top: dynamics packed as float2 (v_pk_fma_f32 / v_pk_add_f32, full-rate
// dual f32) -- saves ~5 inst/step. Structure is otherwise the measured-best
// R13/R14 skeleton: 1 element/wave, barrier-free, f16 LDS y-exchange,
// select-free DPP butterfly, input row in LDS, next-step input prefetch.
__global__
__attribute__((amdgpu_flat_work_group_size(64, 64), amdgpu_waves_per_eu(1, 4)))
void horn_kernel(
    const float* __restrict__ input,   // (1024, 784)
    const float* __restrict__ w_ih,    // (94, 1)
    const float* __restrict__ b_ih,    // (94)
    const float* __restrict__ w_hh,    // (94, 94)
    const float* __restrict__ b_hh,    // (94)
    const float* __restrict__ w_ro,    // (10, 94)
    const float* __restrict__ b_ro,    // (10)
    float* __restrict__ out)           // (1024, 10)
{
    __shared__ __align__(16) _Float16 ysh[96];        // y exchange (f16)
    __shared__ __align__(16) float    sin_l[SEQ_LEN]; // input row (f32)
    __shared__ __align__(16) float    xsh[96];        // epilogue x gather

    const int lane = threadIdx.x;      // 0..63
    const int g    = lane >> 3;        // row-group: rows 12g..12g+11
    const int lw   = lane & 7;         // col-chunk: cols 12lw..12lw+11
    const int bb   = blockIdx.x;       // batch element

    const int b0  = lane & 1, b1 = (lane >> 1) & 1, b2v = (lane >> 2) & 1;
    const int c0i = b0 ^ b2v;
    const int c1i = b1 ^ b2v;
    const int c2i = b2v;

    const int row0 = 12 * g, col0 = 12 * lw;

    // ---- preload input row to LDS (784 floats, float4-coalesced) ----
    {
        const f4* in4 = (const f4*)(input + (size_t)bb * SEQ_LEN);
        f4* s4 = (f4*)sin_l;
        #pragma unroll 1
        for (int i = lane; i < SEQ_LEN / 4; i += 64) s4[i] = in4[i];
    }

    // ---- W block with folded row permutation (select-free butterfly),
    //      f16-packed, pre-scaled ----
    h2 w2[12][6];
    #pragma unroll
    for (int j = 0; j < 12; j++) {
        int rr;
        if (j < 8) {
            rr = row0 + 4 * (((j >> 2) & 1) ^ c2i)
                      + 2 * (((j >> 1) & 1) ^ c1i)
                      +     ((j & 1) ^ c0i);
        } else {
            const int jj = j - 8;
            rr = row0 + 8 + 2 * (((jj >> 1) & 1) ^ c1i)
                          +     ((jj & 1) ^ c0i);
        }
        #pragma unroll
        for (int c = 0; c < 12; c++) {
            const int cc = col0 + c;
            float v = (rr < NUM_NODES && cc < NUM_NODES)
                        ? w_hh[rr * NUM_NODES + cc] * WSCALE : 0.0f;
            w2[j][c >> 1][c & 1] = (_Float16)v;
        }
    }

    // Owned rows (verified machinery R6-R15):
    const int nA = row0 + 4 * c2i + 2 * c1i + c0i;
    const int nB = row0 + 8 + 2 * c1i + c0i;
    const f2 wih2  = { (nA < NUM_NODES) ? w_ih[nA] * WSCALE : 0.0f,
                       (nB < NUM_NODES) ? w_ih[nB] * WSCALE : 0.0f };
    const f2 bias2 = { (nA < NUM_NODES) ? (b_ih[nA] + b_hh[nA]) * WSCALE : 0.0f,
                       (nB < NUM_NODES) ? (b_ih[nB] + b_hh[nB]) * WSCALE : 0.0f };

    f2 xv = {0.0f, 0.0f};              // {xA, xB}
    f2 yv = {0.0f, 0.0f};              // {yA, yB}

    // Init published y (nA unique over 64 lanes, nB pair-duplicated).
    ysh[nA] = (_Float16)0.0f;
    ysh[nB] = (_Float16)0.0f;
    // One-time ordering point: init writes + input preload before the loop.
    asm volatile("s_waitcnt lgkmcnt(0) vmcnt(0)" ::: "memory");

    const h4* yv4 = (const h4*)&ysh[col0];     // byte 24*lw: 8B-aligned

    float st = sin_l[0];                       // step-0 input (prefetched)

    #pragma unroll 2
    for (int t = 0; t < SEQ_LEN; t++) {
        // ---- read own 12-col y chunk; prefetch NEXT step's input scalar ----
        h4 Y0 = yv4[0], Y1 = yv4[1], Y2 = yv4[2];
        const int tn = (t + 1 < SEQ_LEN) ? t + 1 : (SEQ_LEN - 1);
        float stn = sin_l[tn];
        h2 yy0 = __builtin_shufflevector(Y0, Y0, 0, 1);
        h2 yy1 = __builtin_shufflevector(Y0, Y0, 2, 3);
        h2 yy2 = __builtin_shufflevector(Y1, Y1, 0, 1);
        h2 yy3 = __builtin_shufflevector(Y1, Y1, 2, 3);
        h2 yy4 = __builtin_shufflevector(Y2, Y2, 0, 1);
        h2 yy5 = __builtin_shufflevector(Y2, Y2, 2, 3);

        // ---- 12 rows x 12 cols: 72 v_dot2_f32_f16 (f32 accumulate) ----
        float P[12];
        #pragma unroll
        for (int i = 0; i < 12; i++) {
            float p = dot2(w2[i][0], yy0, 0.0f);
            p = dot2(w2[i][1], yy1, p);
            p = dot2(w2[i][2], yy2, p);
            p = dot2(w2[i][3], yy3, p);
            p = dot2(w2[i][4], yy4, p);
            p = dot2(w2[i][5], yy5, p);
            P[i] = p;
        }

        // ---- select-free butterfly (row permutation folded at load) ----
        float Q0 = P[0]  + dpp_xor1(P[1]);
        float Q1 = P[2]  + dpp_xor1(P[3]);
        float Q2 = P[4]  + dpp_xor1(P[5]);
        float Q3 = P[6]  + dpp_xor1(P[7]);
        float Q4 = P[8]  + dpp_xor1(P[9]);
        float Q5 = P[10] + dpp_xor1(P[11]);
        float R0 = Q0 + dpp_xor2(Q1);
        float R1 = Q2 + dpp_xor2(Q3);
        float R2 = Q4 + dpp_xor2(Q5);
        float SA = R0 + dpp_mir8(R1);          // full dot, row nA
        float SB = R2 + dpp_mir8(R2);          // full dot, row nB

        // ---- dynamics, packed f32 (v_pk_fma_f32 / v_pk_add_f32) ----
        f2 stv = {st, st};
        f2 Sv  = {SA, SB};
        f2 ev;
        {
            f2 earg = stv * wih2 + bias2 + Sv;         // pk_fma + pk_add
            ev[0] = __builtin_amdgcn_exp2f(earg[0]);   // transcendental: scalar
            ev[1] = __builtin_amdgcn_exp2f(earg[1]);
        }
        f2 av;
        av[0] = 0.5f - __builtin_amdgcn_rcpf(ev[0] + 1.0f);   // 0.5*tanh(A)
        av[1] = 0.5f - __builtin_amdgcn_rcpf(ev[1] + 1.0f);
        {
            const f2 ng = {-TWO_GAMMA, -TWO_GAMMA};
            const f2 no = {-OM2, -OM2};
            av = ng * yv + av;                 // pk_fma
            av = no * xv + av;                 // pk_fma
        }
        xv = xv + yv;                          // pk_add  (H = 1)
        yv = yv + av;                          // pk_add

        // ---- publish new y (f16; no fence: DS pipe is in-order per wave,
        //      next iteration's ds_read is ordered after these writes) ----
        ysh[nA] = (_Float16)yv[0];
        ysh[nB] = (_Float16)yv[1];             // pair-duplicate: benign

        st = stn;
    }

    // ---- epilogue: gather x (f32), project to classes ----
    xsh[nA] = xv[0];
    xsh[nB] = xv[1];
    asm volatile("s_waitcnt lgkmcnt(0)" ::: "memory");

    if (lane < OUT_CLASSES) {
        float acc = b_ro[lane];
        #pragma unroll 2
        for (int j = 0; j < NUM_NODES; j++) {
            acc += xsh[j] * w_ro[lane * NUM_NODES + j];
        }
        out[(size_t)bb * OUT_CLASSES + lane] = acc;
    }
}

extern "C" void kernel_launch(void* const* d_in, const int* in_sizes, int n_in,
                              void* d_out, int out_size, void* d_ws, size_t ws_size,
                              hipStream_t stream) {
    const float* input = (const float*)d_in[0];
    const float* w_ih  = (const float*)d_in[1];
    const float* b_ih  = (const float*)d_in[2];
    const float* w_hh  = (const float*)d_in[3];
    const float* b_hh  = (const float*)d_in[4];
    const float* w_ro  = (const float*)d_in[5];
    const float* b_ro  = (const float*)d_in[6];
    float* out = (float*)d_out;

    const int batch = in_sizes[0] / SEQ_LEN;   // 1024
    dim3 grid(batch);                          // 1 element per 1-wave block
    dim3 block(64);

    hipLaunchKernelGGL(horn_kernel, grid, block, 0, stream,
                       input, w_ih, b_ih, w_hh, b_hh, w_ro, b_ro, out);
}